// Round 10
// baseline (1242.501 us; speedup 1.0000x reference)
//
#include <hip/hip_runtime.h>

// GIN forward, bf16 inter-stage tensors:
//   h16a = bf16(x @ W_pre.T + b_pre)
//   h16b = bf16(relu((h16a + seg_sum(h16a[src])) @ W_first.T + b_first))
//   out  = (h16b + seg_sum(h16b[src])) @ W_out.T + b_out   (f32)
// N=100000, E=1600000.
// R10: buckets = 64 nodes = one conv block -> p_bucket deleted. Conv gather is
// edge-parallel (equal contiguous edge chunks per 8-lane group) accumulating
// into an LDS f32 tile via ds_add_f32 -> no per-node divergence. MFMA A-frags
// convert f32->bf16 on the fly. 26.6KB LDS -> 6 blocks/CU.

using bf16x8 = __attribute__((ext_vector_type(8))) short;
using f32x4  = __attribute__((ext_vector_type(4))) float;

__device__ inline unsigned short f2bf(float f) {
    unsigned b = __float_as_uint(f);
    return (unsigned short)((b + 0x7FFF + ((b >> 16) & 1)) >> 16);
}
__device__ inline float bf2f_lo(unsigned u) { return __uint_as_float(u << 16); }
__device__ inline float bf2f_hi(unsigned u) { return __uint_as_float(u & 0xFFFF0000u); }

constexpr int CHUNK = 8192;

// ---------------------------------------------------------------------------
// K1: blocks [0,GB) = pre-GEMM h16a = bf16(x@W_pre.T+b_pre), K=128 (R9 tile);
//     blocks [GB,GB+NC) = per-chunk 64-node-bucket histogram.
// ---------------------------------------------------------------------------
__global__ __launch_bounds__(256) void k1_pre_hist(
    const float* __restrict__ x, const float* __restrict__ Wp,
    const float* __restrict__ bp, unsigned short* __restrict__ h16a, int N,
    const int* __restrict__ dst, int* __restrict__ counts,
    int E, int NBK, int NC, int GB)
{
    __shared__ char lds_raw[34816];                // 8704 ints >= NBK=1563
    const int tid = threadIdx.x;

    if (blockIdx.x >= GB) {                        // ---- histogram role ----
        int* cnt = (int*)lds_raw;
        const int c = blockIdx.x - GB;
        for (int b = tid; b < NBK; b += 256) cnt[b] = 0;
        __syncthreads();
        const int beg = c * CHUNK, end = min(beg + CHUNK, E);
        for (int e = beg + tid; e < end; e += 256)
            atomicAdd(&cnt[dst[e] >> 6], 1);
        __syncthreads();
        for (int b = tid; b < NBK; b += 256) counts[b * NC + c] = cnt[b];
        return;
    }

    // ---- GEMM role ----
    constexpr int SP = 136;
    unsigned short (*xs)[SP] = (unsigned short(*)[SP])lds_raw;
    unsigned short (*ws)[SP] = (unsigned short(*)[SP])(lds_raw + 64 * SP * 2);
    const int base = blockIdx.x * 64;

    for (int i = tid; i < 64 * 32; i += 256) {     // stage W_pre -> bf16
        const int r = i >> 5, q = i & 31;
        const float4 v = *(const float4*)(Wp + r * 128 + q * 4);
        *(ushort4*)&ws[r][q * 4] =
            make_ushort4(f2bf(v.x), f2bf(v.y), f2bf(v.z), f2bf(v.w));
    }
    for (int i = tid; i < 64 * 32; i += 256) {     // stage x -> bf16
        const int r = i >> 5, q = i & 31;
        int row = base + r; if (row > N - 1) row = N - 1;
        const float4 v = *(const float4*)(x + (size_t)row * 128 + q * 4);
        *(ushort4*)&xs[r][q * 4] =
            make_ushort4(f2bf(v.x), f2bf(v.y), f2bf(v.z), f2bf(v.w));
    }
    __syncthreads();

    const int w = tid >> 6, l = tid & 63, lr = l & 15, lg = l >> 4;
    f32x4 acc[4];
#pragma unroll
    for (int nb = 0; nb < 4; ++nb) {
        const float bv = bp[nb * 16 + lr];
        acc[nb] = (f32x4){bv, bv, bv, bv};
    }
#pragma unroll
    for (int kb = 0; kb < 4; ++kb) {
        const bf16x8 a = *(const bf16x8*)&xs[w * 16 + lr][kb * 32 + lg * 8];
#pragma unroll
        for (int nb = 0; nb < 4; ++nb) {
            const bf16x8 b = *(const bf16x8*)&ws[nb * 16 + lr][kb * 32 + lg * 8];
            acc[nb] = __builtin_amdgcn_mfma_f32_16x16x32_bf16(a, b, acc[nb], 0, 0, 0);
        }
    }
#pragma unroll
    for (int nb = 0; nb < 4; ++nb) {
#pragma unroll
        for (int r = 0; r < 4; ++r) {
            const int row = base + w * 16 + lg * 4 + r;
            if (row < N)
                h16a[(size_t)row * 64 + nb * 16 + lr] = f2bf(acc[nb][r]);
        }
    }
}

// ---------------------------------------------------------------------------
// Fused conv, edge-parallel: block = 64-node bucket. Gather: equal contiguous
// edge chunks per 8-lane group; bf16->f32; ds_add_f32 into xsf. MFMA K=64.
// ---------------------------------------------------------------------------
__device__ inline void atom8(float* d, const uint4 u) {
    atomicAdd(d + 0, bf2f_lo(u.x)); atomicAdd(d + 1, bf2f_hi(u.x));
    atomicAdd(d + 2, bf2f_lo(u.y)); atomicAdd(d + 3, bf2f_hi(u.y));
    atomicAdd(d + 4, bf2f_lo(u.z)); atomicAdd(d + 5, bf2f_hi(u.z));
    atomicAdd(d + 6, bf2f_lo(u.w)); atomicAdd(d + 7, bf2f_hi(u.w));
}

template <int RELU, int WF32>
__global__ __launch_bounds__(256) void conv_fused(
    const unsigned short* __restrict__ hin, const unsigned* __restrict__ slots,
    const int* __restrict__ counts, const float* __restrict__ W,
    const float* __restrict__ bias, float* __restrict__ outf,
    unsigned short* __restrict__ out16, int N, int E, int NC, int NBK)
{
    constexpr int SPF = 68;                        // f32 tile stride (dwords)
    constexpr int SPW = 72;                        // ws stride (ushorts)
    __shared__ float xsf[64][SPF];                 // 17,408 B
    __shared__ unsigned short ws[64][SPW];         //  9,216 B
    const int tid  = threadIdx.x;
    const int blk  = blockIdx.x;
    const int base = blk * 64;

    for (int i = tid; i < 64 * 16; i += 256) {     // stage W -> bf16
        const int r = i >> 4, q = i & 15;
        const float4 v = *(const float4*)(W + r * 64 + q * 4);
        *(ushort4*)&ws[r][q * 4] =
            make_ushort4(f2bf(v.x), f2bf(v.y), f2bf(v.z), f2bf(v.w));
    }

    {   // init xsf with self term (64 rows x 4 chunks of 16 f32)
        const int r  = tid >> 2;
        const int cb = (tid & 3) * 16;
        const int node = base + r;
        float* dp = &xsf[r][cb];
        if (node < N) {
            const uint4 u0 = *(const uint4*)(hin + (size_t)node * 64 + cb);
            const uint4 u1 = *(const uint4*)(hin + (size_t)node * 64 + cb + 8);
            dp[0]  = bf2f_lo(u0.x); dp[1]  = bf2f_hi(u0.x);
            dp[2]  = bf2f_lo(u0.y); dp[3]  = bf2f_hi(u0.y);
            dp[4]  = bf2f_lo(u0.z); dp[5]  = bf2f_hi(u0.z);
            dp[6]  = bf2f_lo(u0.w); dp[7]  = bf2f_hi(u0.w);
            dp[8]  = bf2f_lo(u1.x); dp[9]  = bf2f_hi(u1.x);
            dp[10] = bf2f_lo(u1.y); dp[11] = bf2f_hi(u1.y);
            dp[12] = bf2f_lo(u1.z); dp[13] = bf2f_hi(u1.z);
            dp[14] = bf2f_lo(u1.w); dp[15] = bf2f_hi(u1.w);
        } else {
#pragma unroll
            for (int i = 0; i < 16; ++i) dp[i] = 0.f;
        }
    }
    __syncthreads();

    // ---- edge-parallel gather ----
    const int beg = counts[blk * NC];
    const int end = (blk + 1 < NBK) ? counts[(blk + 1) * NC] : E;
    const int cnt = end - beg;
    const int g   = tid >> 3;                      // group 0..31
    const int c   = (tid & 7) * 8;                 // col offset (elems)
    int j  = beg + (cnt * g)       / 32;
    const int hi = beg + (cnt * (g + 1)) / 32;

    for (; j + 4 <= hi; j += 4) {                  // 4 rows in flight
        const unsigned p0 = slots[j],     p1 = slots[j + 1];
        const unsigned p2 = slots[j + 2], p3 = slots[j + 3];
        const uint4 u0 = *(const uint4*)(hin + (size_t)(p0 & 0xFFFFFFu) * 64 + c);
        const uint4 u1 = *(const uint4*)(hin + (size_t)(p1 & 0xFFFFFFu) * 64 + c);
        const uint4 u2 = *(const uint4*)(hin + (size_t)(p2 & 0xFFFFFFu) * 64 + c);
        const uint4 u3 = *(const uint4*)(hin + (size_t)(p3 & 0xFFFFFFu) * 64 + c);
        atom8(&xsf[p0 >> 24][c], u0);
        atom8(&xsf[p1 >> 24][c], u1);
        atom8(&xsf[p2 >> 24][c], u2);
        atom8(&xsf[p3 >> 24][c], u3);
    }
    for (; j < hi; ++j) {
        const unsigned p0 = slots[j];
        const uint4 u0 = *(const uint4*)(hin + (size_t)(p0 & 0xFFFFFFu) * 64 + c);
        atom8(&xsf[p0 >> 24][c], u0);
    }
    __syncthreads();

    // ---- MFMA phase: A-frag cvt f32->bf16 on the fly ----
    const int w = tid >> 6, l = tid & 63, lr = l & 15, lg = l >> 4;
    f32x4 acc[4];
#pragma unroll
    for (int nb = 0; nb < 4; ++nb) {
        const float bv = bias[nb * 16 + lr];
        acc[nb] = (f32x4){bv, bv, bv, bv};
    }
#pragma unroll
    for (int kb = 0; kb < 2; ++kb) {
        const float* ap = &xsf[w * 16 + lr][kb * 32 + lg * 8];
        bf16x8 a;
#pragma unroll
        for (int i = 0; i < 8; ++i) a[i] = (short)f2bf(ap[i]);
#pragma unroll
        for (int nb = 0; nb < 4; ++nb) {
            const bf16x8 b = *(const bf16x8*)&ws[nb * 16 + lr][kb * 32 + lg * 8];
            acc[nb] = __builtin_amdgcn_mfma_f32_16x16x32_bf16(a, b, acc[nb], 0, 0, 0);
        }
    }
#pragma unroll
    for (int nb = 0; nb < 4; ++nb) {
#pragma unroll
        for (int r = 0; r < 4; ++r) {
            const int row = base + w * 16 + lg * 4 + r;
            if (row < N) {
                float v = acc[nb][r];
                if (RELU) v = fmaxf(v, 0.f);
                if (WF32) outf[(size_t)row * 64 + nb * 16 + lr] = v;
                else      out16[(size_t)row * 64 + nb * 16 + lr] = f2bf(v);
            }
        }
    }
}

// ---------------------------------------------------------------------------
// Scan chain (512-thread blocks; partial <= 1024) + chunk scatter.
// ---------------------------------------------------------------------------
__global__ __launch_bounds__(512) void k_blocksum(
    const int* __restrict__ in, int* __restrict__ partial, int n)
{
    __shared__ int s[512];
    const int i = blockIdx.x * 512 + threadIdx.x;
    s[threadIdx.x] = (i < n) ? in[i] : 0;
    __syncthreads();
    for (int off = 256; off > 0; off >>= 1) {
        if (threadIdx.x < off) s[threadIdx.x] += s[threadIdx.x + off];
        __syncthreads();
    }
    if (threadIdx.x == 0) partial[blockIdx.x] = s[0];
}

__global__ __launch_bounds__(1024) void k_scanpartial1024(
    int* __restrict__ partial, int nblk)
{
    __shared__ int s[1024];
    const int t = threadIdx.x;
    s[t] = (t < nblk) ? partial[t] : 0;
    __syncthreads();
    for (int off = 1; off < 1024; off <<= 1) {
        const int v = (t >= off) ? s[t - off] : 0;
        __syncthreads();
        s[t] += v;
        __syncthreads();
    }
    if (t < nblk) partial[t] = (t == 0) ? 0 : s[t - 1];
}

__global__ __launch_bounds__(512) void k_exscan(
    int* __restrict__ data, const int* __restrict__ partial, int n)
{
    __shared__ int s[512];
    const int i = blockIdx.x * 512 + threadIdx.x;
    const int t = threadIdx.x;
    const int v = (i < n) ? data[i] : 0;
    s[t] = v;
    __syncthreads();
    for (int off = 1; off < 512; off <<= 1) {
        const int u = (t >= off) ? s[t - off] : 0;
        __syncthreads();
        s[t] += u;
        __syncthreads();
    }
    if (i < n) data[i] = partial[blockIdx.x] + s[t] - v;   // exclusive
}

__global__ __launch_bounds__(256) void p_scatter(
    const int* __restrict__ src, const int* __restrict__ dst,
    const int* __restrict__ counts, unsigned* __restrict__ slots,
    int E, int NBK, int NC)
{
    __shared__ int cur[1600];                      // NBK <= 1600
    const int c = blockIdx.x;
    for (int b = threadIdx.x; b < NBK; b += 256) cur[b] = counts[b * NC + c];
    __syncthreads();
    const int beg = c * CHUNK;
    const int end = min(beg + CHUNK, E);
    for (int e = beg + threadIdx.x; e < end; e += 256) {
        const int d = dst[e];
        const int pos = atomicAdd(&cur[d >> 6], 1);
        slots[pos] = ((unsigned)(d & 63) << 24) | (unsigned)src[e];
    }
}

extern "C" void kernel_launch(void* const* d_in, const int* in_sizes, int n_in,
                              void* d_out, int out_size, void* d_ws, size_t ws_size,
                              hipStream_t stream)
{
    const float* x       = (const float*)d_in[0];
    const int*   ei      = (const int*)  d_in[1];
    const float* W_pre   = (const float*)d_in[2];
    const float* b_pre   = (const float*)d_in[3];
    const float* W_first = (const float*)d_in[4];
    const float* b_first = (const float*)d_in[5];
    const float* W_out   = (const float*)d_in[6];
    const float* b_out   = (const float*)d_in[7];

    const int N = in_sizes[0] / 128;
    const int E = in_sizes[1] / 2;
    const int* src = ei;
    const int* dst = ei + E;

    const int NBK   = (N + 63) / 64;              // 1563 buckets = conv blocks
    const int NC    = (E + CHUNK - 1) / CHUNK;    // 196 chunks
    const int nscan = NBK * NC;                   // 306,348
    const int nsblk = (nscan + 511) / 512;        // 599 <= 1024

    // Workspace (~33.3 MB):
    unsigned short* h16a   = (unsigned short*)d_ws;              // [N*64]
    unsigned short* h16b   = h16a + (size_t)N * 64;              // [N*64]
    unsigned*       slots  = (unsigned*)(h16b + (size_t)N * 64); // [E]
    int*            counts = (int*)(slots + E);                  // [nscan]
    int*            partial= counts + nscan;                     // [<=1024]

    float* out = (float*)d_out;
    const int GB = (N + 63) / 64;                 // 1563 pre-GEMM blocks

    // K1: pre-GEMM || bucket histogram
    k1_pre_hist<<<GB + NC, 256, 0, stream>>>(
        x, W_pre, b_pre, h16a, N, dst, counts, E, NBK, NC, GB);

    // scan chain over counts (bucket-major)
    k_blocksum<<<nsblk, 512, 0, stream>>>(counts, partial, nscan);
    k_scanpartial1024<<<1, 1024, 0, stream>>>(partial, nsblk);
    k_exscan<<<nsblk, 512, 0, stream>>>(counts, partial, nscan);

    // scatter edges into bucket-contiguous regions (packed dstLocal|src)
    p_scatter<<<NC, 256, 0, stream>>>(src, dst, counts, slots, E, NBK, NC);

    // conv1 fused -> h16b (bf16, relu)
    conv_fused<1, 0><<<NBK, 256, 0, stream>>>(
        h16a, slots, counts, W_first, b_first, nullptr, h16b, N, E, NC, NBK);

    // conv2 fused -> d_out (f32)
    conv_fused<0, 1><<<NBK, 256, 0, stream>>>(
        h16b, slots, counts, W_out, b_out, out, nullptr, N, E, NC, NBK);
}

// Round 11
// 137.207 us; speedup vs baseline: 9.0557x; 9.0557x over previous
//
#include <hip/hip_runtime.h>

// GIN forward, bf16 inter-stage tensors:
//   h16a = bf16(x @ W_pre.T + b_pre)
//   h16b = bf16(relu((h16a + seg_sum(h16a[src])) @ W_first.T + b_first))
//   out  = (h16b + seg_sum(h16b[src])) @ W_out.T + b_out   (f32)
// N=100000, E=1600000.
// R11: R10's f32-LDS-atomic edge-parallel gather was a 14x regression (CAS
// loops, VALUBusy 1.4%). Conv rebuilt: per-block LDS counting sort of the
// bucket's edges (u32 LDS atomics only - native ds_add) + per-node register
// walk reading slot ids from LDS, with work-stealing node assignment to kill
// Poisson-degree imbalance. p_bucket stays deleted.

using bf16x8 = __attribute__((ext_vector_type(8))) short;
using f32x4  = __attribute__((ext_vector_type(4))) float;

__device__ inline unsigned short f2bf(float f) {
    unsigned b = __float_as_uint(f);
    return (unsigned short)((b + 0x7FFF + ((b >> 16) & 1)) >> 16);
}
__device__ inline float bf2f_lo(unsigned u) { return __uint_as_float(u << 16); }
__device__ inline float bf2f_hi(unsigned u) { return __uint_as_float(u & 0xFFFF0000u); }
__device__ inline unsigned packbf(float lo, float hi) {
    return (unsigned)f2bf(lo) | ((unsigned)f2bf(hi) << 16);
}
__device__ inline void acc8(float* a, const uint4 u) {
    a[0] += bf2f_lo(u.x); a[1] += bf2f_hi(u.x);
    a[2] += bf2f_lo(u.y); a[3] += bf2f_hi(u.y);
    a[4] += bf2f_lo(u.z); a[5] += bf2f_hi(u.z);
    a[6] += bf2f_lo(u.w); a[7] += bf2f_hi(u.w);
}

constexpr int CHUNK = 8192;
constexpr int LCAP  = 2048;   // LDS edge capacity; Poisson(1024)+32sigma unreachable

// ---------------------------------------------------------------------------
// K1: blocks [0,GB) = pre-GEMM h16a = bf16(x@W_pre.T+b_pre), K=128;
//     blocks [GB,GB+NC) = per-chunk 64-node-bucket histogram.
// ---------------------------------------------------------------------------
__global__ __launch_bounds__(256) void k1_pre_hist(
    const float* __restrict__ x, const float* __restrict__ Wp,
    const float* __restrict__ bp, unsigned short* __restrict__ h16a, int N,
    const int* __restrict__ dst, int* __restrict__ counts,
    int E, int NBK, int NC, int GB)
{
    __shared__ char lds_raw[34816];                // 8704 ints >= NBK=1563
    const int tid = threadIdx.x;

    if (blockIdx.x >= GB) {                        // ---- histogram role ----
        int* cnt = (int*)lds_raw;
        const int c = blockIdx.x - GB;
        for (int b = tid; b < NBK; b += 256) cnt[b] = 0;
        __syncthreads();
        const int beg = c * CHUNK, end = min(beg + CHUNK, E);
        for (int e = beg + tid; e < end; e += 256)
            atomicAdd(&cnt[dst[e] >> 6], 1);
        __syncthreads();
        for (int b = tid; b < NBK; b += 256) counts[b * NC + c] = cnt[b];
        return;
    }

    // ---- GEMM role ----
    constexpr int SP = 136;
    unsigned short (*xs)[SP] = (unsigned short(*)[SP])lds_raw;
    unsigned short (*ws)[SP] = (unsigned short(*)[SP])(lds_raw + 64 * SP * 2);
    const int base = blockIdx.x * 64;

    for (int i = tid; i < 64 * 32; i += 256) {     // stage W_pre -> bf16
        const int r = i >> 5, q = i & 31;
        const float4 v = *(const float4*)(Wp + r * 128 + q * 4);
        *(ushort4*)&ws[r][q * 4] =
            make_ushort4(f2bf(v.x), f2bf(v.y), f2bf(v.z), f2bf(v.w));
    }
    for (int i = tid; i < 64 * 32; i += 256) {     // stage x -> bf16
        const int r = i >> 5, q = i & 31;
        int row = base + r; if (row > N - 1) row = N - 1;
        const float4 v = *(const float4*)(x + (size_t)row * 128 + q * 4);
        *(ushort4*)&xs[r][q * 4] =
            make_ushort4(f2bf(v.x), f2bf(v.y), f2bf(v.z), f2bf(v.w));
    }
    __syncthreads();

    const int w = tid >> 6, l = tid & 63, lr = l & 15, lg = l >> 4;
    f32x4 acc[4];
#pragma unroll
    for (int nb = 0; nb < 4; ++nb) {
        const float bv = bp[nb * 16 + lr];
        acc[nb] = (f32x4){bv, bv, bv, bv};
    }
#pragma unroll
    for (int kb = 0; kb < 4; ++kb) {
        const bf16x8 a = *(const bf16x8*)&xs[w * 16 + lr][kb * 32 + lg * 8];
#pragma unroll
        for (int nb = 0; nb < 4; ++nb) {
            const bf16x8 b = *(const bf16x8*)&ws[nb * 16 + lr][kb * 32 + lg * 8];
            acc[nb] = __builtin_amdgcn_mfma_f32_16x16x32_bf16(a, b, acc[nb], 0, 0, 0);
        }
    }
#pragma unroll
    for (int nb = 0; nb < 4; ++nb) {
#pragma unroll
        for (int r = 0; r < 4; ++r) {
            const int row = base + w * 16 + lg * 4 + r;
            if (row < N)
                h16a[(size_t)row * 64 + nb * 16 + lr] = f2bf(acc[nb][r]);
        }
    }
}

// ---------------------------------------------------------------------------
// Fused conv: block = 64-node bucket. Phase A: LDS counting sort of the
// bucket's packed edges (u32 LDS atomics). Phase B: per-node register walk
// (8 lanes/node, 8-deep, slot ids from LDS) with work-stealing. Phase C: MFMA.
// ---------------------------------------------------------------------------
template <int RELU, int WF32>
__global__ __launch_bounds__(256) void conv_fused(
    const unsigned short* __restrict__ hin, const unsigned* __restrict__ slots,
    const int* __restrict__ counts, const float* __restrict__ W,
    const float* __restrict__ bias, float* __restrict__ outf,
    unsigned short* __restrict__ out16, int N, int E, int NC, int NBK)
{
    constexpr int SPW = 72;                        // bf16 tile stride
    __shared__ unsigned short ws[64][SPW];         // 9216 B
    __shared__ unsigned short xs[64][SPW];         // 9216 B
    __shared__ unsigned lsl[LCAP];                 // 8192 B sorted src ids
    __shared__ int hist[64], sc[64], cur[64], loffs[65], steal;

    const int tid  = threadIdx.x;
    const int blk  = blockIdx.x;
    const int base = blk * 64;

    for (int i = tid; i < 64 * 16; i += 256) {     // stage W -> bf16
        const int r = i >> 4, q = i & 15;
        const float4 v = *(const float4*)(W + r * 64 + q * 4);
        *(ushort4*)&ws[r][q * 4] =
            make_ushort4(f2bf(v.x), f2bf(v.y), f2bf(v.z), f2bf(v.w));
    }

    const int beg = counts[blk * NC];
    const int end = (blk + 1 < NBK) ? counts[(blk + 1) * NC] : E;
    const int cnt  = end - beg;
    const int cntc = min(cnt, LCAP);

    if (tid < 64) hist[tid] = 0;
    if (tid == 0) steal = 0;
    __syncthreads();

    // ---- Phase A: load packed edges to regs, histogram, scan, scatter ----
    unsigned pk[8];
#pragma unroll
    for (int t = 0; t < 8; ++t) {
        const int i = tid + t * 256;
        pk[t] = (i < cntc) ? slots[beg + i] : 0xFFFFFFFFu;
    }
#pragma unroll
    for (int t = 0; t < 8; ++t)
        if (pk[t] != 0xFFFFFFFFu) atomicAdd(&hist[pk[t] >> 24], 1);
    __syncthreads();

    if (tid < 64) sc[tid] = hist[tid];             // Hillis-Steele over 64
    __syncthreads();
    for (int off = 1; off < 64; off <<= 1) {
        int v = 0;
        if (tid < 64 && tid >= off) v = sc[tid - off];
        __syncthreads();
        if (tid < 64) sc[tid] += v;
        __syncthreads();
    }
    if (tid < 64) {
        const int ex = sc[tid] - hist[tid];        // exclusive
        loffs[tid] = ex;
        cur[tid]   = ex;
        if (tid == 63) loffs[64] = sc[63];
    }
    __syncthreads();

#pragma unroll
    for (int t = 0; t < 8; ++t)
        if (pk[t] != 0xFFFFFFFFu) {
            const int pos = atomicAdd(&cur[pk[t] >> 24], 1);
            lsl[pos] = pk[t] & 0x00FFFFFFu;
        }
    __syncthreads();

    // ---- Phase B: per-node walk, work-stealing over 64 nodes ----
    const int l = tid & 63;
    const int leader = l & ~7;                     // 8-lane group leader
    const int c = (l & 7) * 8;                     // col offset (elems)
    while (true) {
        int n = 0;
        if ((l & 7) == 0) n = atomicAdd(&steal, 1);
        n = __shfl(n, leader);
        if (n >= 64) break;
        const int node = base + n;
        float a[8] = {0.f, 0.f, 0.f, 0.f, 0.f, 0.f, 0.f, 0.f};
        if (node < N) {
            acc8(a, *(const uint4*)(hin + (size_t)node * 64 + c));  // self
            int j = loffs[n];
            const int hi = loffs[n + 1];
            for (; j + 8 <= hi; j += 8) {          // 8 rows in flight
                const unsigned s0 = lsl[j],     s1 = lsl[j + 1];
                const unsigned s2 = lsl[j + 2], s3 = lsl[j + 3];
                const unsigned s4 = lsl[j + 4], s5 = lsl[j + 5];
                const unsigned s6 = lsl[j + 6], s7 = lsl[j + 7];
                const uint4 u0 = *(const uint4*)(hin + (size_t)s0 * 64 + c);
                const uint4 u1 = *(const uint4*)(hin + (size_t)s1 * 64 + c);
                const uint4 u2 = *(const uint4*)(hin + (size_t)s2 * 64 + c);
                const uint4 u3 = *(const uint4*)(hin + (size_t)s3 * 64 + c);
                const uint4 u4 = *(const uint4*)(hin + (size_t)s4 * 64 + c);
                const uint4 u5 = *(const uint4*)(hin + (size_t)s5 * 64 + c);
                const uint4 u6 = *(const uint4*)(hin + (size_t)s6 * 64 + c);
                const uint4 u7 = *(const uint4*)(hin + (size_t)s7 * 64 + c);
                acc8(a, u0); acc8(a, u1); acc8(a, u2); acc8(a, u3);
                acc8(a, u4); acc8(a, u5); acc8(a, u6); acc8(a, u7);
            }
            for (; j + 4 <= hi; j += 4) {
                const unsigned s0 = lsl[j],     s1 = lsl[j + 1];
                const unsigned s2 = lsl[j + 2], s3 = lsl[j + 3];
                const uint4 u0 = *(const uint4*)(hin + (size_t)s0 * 64 + c);
                const uint4 u1 = *(const uint4*)(hin + (size_t)s1 * 64 + c);
                const uint4 u2 = *(const uint4*)(hin + (size_t)s2 * 64 + c);
                const uint4 u3 = *(const uint4*)(hin + (size_t)s3 * 64 + c);
                acc8(a, u0); acc8(a, u1); acc8(a, u2); acc8(a, u3);
            }
            for (; j < hi; ++j)
                acc8(a, *(const uint4*)(hin + (size_t)lsl[j] * 64 + c));
            if (cnt > LCAP) {                      // statistically unreachable
                for (int e2 = beg + LCAP; e2 < end; ++e2) {
                    const unsigned p = slots[e2];
                    if ((int)(p >> 24) == n)
                        acc8(a, *(const uint4*)(hin + (size_t)(p & 0xFFFFFFu) * 64 + c));
                }
            }
        }
        *(uint4*)&xs[n][c] =
            make_uint4(packbf(a[0], a[1]), packbf(a[2], a[3]),
                       packbf(a[4], a[5]), packbf(a[6], a[7]));
    }
    __syncthreads();

    // ---- Phase C: MFMA, K=64 ----
    const int w = tid >> 6, lr = l & 15, lg = l >> 4;
    f32x4 acc[4];
#pragma unroll
    for (int nb = 0; nb < 4; ++nb) {
        const float bv = bias[nb * 16 + lr];
        acc[nb] = (f32x4){bv, bv, bv, bv};
    }
#pragma unroll
    for (int kb = 0; kb < 2; ++kb) {
        const bf16x8 a = *(const bf16x8*)&xs[w * 16 + lr][kb * 32 + lg * 8];
#pragma unroll
        for (int nb = 0; nb < 4; ++nb) {
            const bf16x8 b = *(const bf16x8*)&ws[nb * 16 + lr][kb * 32 + lg * 8];
            acc[nb] = __builtin_amdgcn_mfma_f32_16x16x32_bf16(a, b, acc[nb], 0, 0, 0);
        }
    }
#pragma unroll
    for (int nb = 0; nb < 4; ++nb) {
#pragma unroll
        for (int r = 0; r < 4; ++r) {
            const int row = base + w * 16 + lg * 4 + r;
            if (row < N) {
                float v = acc[nb][r];
                if (RELU) v = fmaxf(v, 0.f);
                if (WF32) outf[(size_t)row * 64 + nb * 16 + lr] = v;
                else      out16[(size_t)row * 64 + nb * 16 + lr] = f2bf(v);
            }
        }
    }
}

// ---------------------------------------------------------------------------
// Scan chain (512-thread blocks; partial <= 1024) + chunk scatter.
// ---------------------------------------------------------------------------
__global__ __launch_bounds__(512) void k_blocksum(
    const int* __restrict__ in, int* __restrict__ partial, int n)
{
    __shared__ int s[512];
    const int i = blockIdx.x * 512 + threadIdx.x;
    s[threadIdx.x] = (i < n) ? in[i] : 0;
    __syncthreads();
    for (int off = 256; off > 0; off >>= 1) {
        if (threadIdx.x < off) s[threadIdx.x] += s[threadIdx.x + off];
        __syncthreads();
    }
    if (threadIdx.x == 0) partial[blockIdx.x] = s[0];
}

__global__ __launch_bounds__(1024) void k_scanpartial1024(
    int* __restrict__ partial, int nblk)
{
    __shared__ int s[1024];
    const int t = threadIdx.x;
    s[t] = (t < nblk) ? partial[t] : 0;
    __syncthreads();
    for (int off = 1; off < 1024; off <<= 1) {
        const int v = (t >= off) ? s[t - off] : 0;
        __syncthreads();
        s[t] += v;
        __syncthreads();
    }
    if (t < nblk) partial[t] = (t == 0) ? 0 : s[t - 1];
}

__global__ __launch_bounds__(512) void k_exscan(
    int* __restrict__ data, const int* __restrict__ partial, int n)
{
    __shared__ int s[512];
    const int i = blockIdx.x * 512 + threadIdx.x;
    const int t = threadIdx.x;
    const int v = (i < n) ? data[i] : 0;
    s[t] = v;
    __syncthreads();
    for (int off = 1; off < 512; off <<= 1) {
        const int u = (t >= off) ? s[t - off] : 0;
        __syncthreads();
        s[t] += u;
        __syncthreads();
    }
    if (i < n) data[i] = partial[blockIdx.x] + s[t] - v;   // exclusive
}

__global__ __launch_bounds__(256) void p_scatter(
    const int* __restrict__ src, const int* __restrict__ dst,
    const int* __restrict__ counts, unsigned* __restrict__ slots,
    int E, int NBK, int NC)
{
    __shared__ int cur[1600];                      // NBK <= 1600
    const int c = blockIdx.x;
    for (int b = threadIdx.x; b < NBK; b += 256) cur[b] = counts[b * NC + c];
    __syncthreads();
    const int beg = c * CHUNK;
    const int end = min(beg + CHUNK, E);
    for (int e = beg + threadIdx.x; e < end; e += 256) {
        const int d = dst[e];
        const int pos = atomicAdd(&cur[d >> 6], 1);
        slots[pos] = ((unsigned)(d & 63) << 24) | (unsigned)src[e];
    }
}

extern "C" void kernel_launch(void* const* d_in, const int* in_sizes, int n_in,
                              void* d_out, int out_size, void* d_ws, size_t ws_size,
                              hipStream_t stream)
{
    const float* x       = (const float*)d_in[0];
    const int*   ei      = (const int*)  d_in[1];
    const float* W_pre   = (const float*)d_in[2];
    const float* b_pre   = (const float*)d_in[3];
    const float* W_first = (const float*)d_in[4];
    const float* b_first = (const float*)d_in[5];
    const float* W_out   = (const float*)d_in[6];
    const float* b_out   = (const float*)d_in[7];

    const int N = in_sizes[0] / 128;
    const int E = in_sizes[1] / 2;
    const int* src = ei;
    const int* dst = ei + E;

    const int NBK   = (N + 63) / 64;              // 1563 buckets = conv blocks
    const int NC    = (E + CHUNK - 1) / CHUNK;    // 196 chunks
    const int nscan = NBK * NC;                   // 306,348
    const int nsblk = (nscan + 511) / 512;        // 599 <= 1024

    // Workspace (~33.3 MB):
    unsigned short* h16a   = (unsigned short*)d_ws;              // [N*64]
    unsigned short* h16b   = h16a + (size_t)N * 64;              // [N*64]
    unsigned*       slots  = (unsigned*)(h16b + (size_t)N * 64); // [E]
    int*            counts = (int*)(slots + E);                  // [nscan]
    int*            partial= counts + nscan;                     // [<=1024]

    float* out = (float*)d_out;
    const int GB = (N + 63) / 64;                 // 1563 pre-GEMM blocks

    // K1: pre-GEMM || bucket histogram
    k1_pre_hist<<<GB + NC, 256, 0, stream>>>(
        x, W_pre, b_pre, h16a, N, dst, counts, E, NBK, NC, GB);

    // scan chain over counts (bucket-major)
    k_blocksum<<<nsblk, 512, 0, stream>>>(counts, partial, nscan);
    k_scanpartial1024<<<1, 1024, 0, stream>>>(partial, nsblk);
    k_exscan<<<nsblk, 512, 0, stream>>>(counts, partial, nscan);

    // scatter edges into bucket-contiguous regions (packed dstLocal|src)
    p_scatter<<<NC, 256, 0, stream>>>(src, dst, counts, slots, E, NBK, NC);

    // conv1 fused -> h16b (bf16, relu)
    conv_fused<1, 0><<<NBK, 256, 0, stream>>>(
        h16a, slots, counts, W_first, b_first, nullptr, h16b, N, E, NC, NBK);

    // conv2 fused -> d_out (f32)
    conv_fused<0, 1><<<NBK, 256, 0, stream>>>(
        h16b, slots, counts, W_out, b_out, out, nullptr, N, E, NC, NBK);
}